// Round 2
// baseline (1008.472 us; speedup 1.0000x reference)
//
#include <hip/hip_runtime.h>

typedef _Float16 f16x8 __attribute__((ext_vector_type(8)));
typedef float f32x4 __attribute__((ext_vector_type(4)));

#define EPS 1e-5f

__device__ __forceinline__ short f2h(float x) {
    _Float16 h = (_Float16)x;   // round-to-nearest-even v_cvt_f16_f32
    union { _Float16 h; short s; } u;
    u.h = h;
    return u.s;
}

// ---------------------------------------------------------------------------
// prep: transpose+convert Wm -> WtM[l][f][k] fp16, Wl -> WtF[f][k] fp16 (f padded
// to 48 with zeros), zero the stats buffers. Runs every call (ws is re-poisoned).
// ---------------------------------------------------------------------------
__global__ void prep_kernel(const float* __restrict__ Wm, const float* __restrict__ Wl,
                            short* __restrict__ WtM, short* __restrict__ WtF,
                            float* __restrict__ stats) {
    const long T1 = 14L * 896 * 128;
    const long T2 = 48L * 896;
    const long T3 = 15L * 256;
    long i = (long)blockIdx.x * blockDim.x + threadIdx.x;
    if (i < T1) {
        long l = i / (896 * 128);
        long r = i % (896 * 128);
        long k = r >> 7;
        long f = r & 127;
        WtM[l * 114688 + f * 896 + k] = f2h(Wm[i]);
    } else if (i < T1 + T2) {
        long j = i - T1;
        long f = j / 896;
        long k = j % 896;
        WtF[j] = (f < 36) ? f2h(Wl[k * 36 + f]) : (short)0;
    } else if (i < T1 + T2 + T3) {
        stats[i - T1 - T2] = 0.0f;
    }
}

// ---------------------------------------------------------------------------
// layer0: h_lin[n,f] = b0[f] + sum_{k<21} x[idx[n,k/3], k%3] * W0[k,f]
// plus per-feature sum / sumsq accumulation. block = 128 threads (one per feat).
// All fp32 — exact.
// ---------------------------------------------------------------------------
__global__ __launch_bounds__(128) void layer0_kernel(
        const float* __restrict__ x, const int* __restrict__ idx,
        const float* __restrict__ W0, const float* __restrict__ b0,
        float* __restrict__ hlin, float* __restrict__ stats, int N) {
    __shared__ float sW[21 * 128];
    __shared__ float smat[21];
    const int tid = threadIdx.x;
    for (int i = tid; i < 21 * 128; i += 128) sW[i] = W0[i];
    const float bf = b0[tid];
    float s = 0.f, ss = 0.f;
    for (int n = blockIdx.x; n < N; n += gridDim.x) {
        __syncthreads();
        if (tid < 21) {
            int j = tid / 3, c = tid - j * 3;
            smat[tid] = x[(long)idx[n * 7 + j] * 3 + c];
        }
        __syncthreads();
        float acc = bf;
#pragma unroll
        for (int k = 0; k < 21; ++k) acc = fmaf(smat[k], sW[k * 128 + tid], acc);
        hlin[(long)n * 128 + tid] = acc;
        s += acc;
        ss += acc * acc;
    }
    atomicAdd(&stats[tid], s);
    atomicAdd(&stats[128 + tid], ss);
}

// ---------------------------------------------------------------------------
// bn_relu: h_out_fp16 = relu(scale[f]*h_lin + shift[f]) with scale/shift folded
// from stats + gamma/beta. total4 = N*128/4.
// ---------------------------------------------------------------------------
__global__ __launch_bounds__(256) void bn_relu_kernel(
        const float* __restrict__ hlin, const float* __restrict__ stats,
        const float* __restrict__ g, const float* __restrict__ be,
        unsigned short* __restrict__ hout, int total4, float invN) {
    __shared__ float sSc[128], sSh[128];
    const int tid = threadIdx.x;
    if (tid < 128) {
        float mu = stats[tid] * invN;
        float var = stats[128 + tid] * invN - mu * mu;
        float rs = rsqrtf(var + EPS);
        float sc = g[tid] * rs;
        sSc[tid] = sc;
        sSh[tid] = be[tid] - mu * sc;
    }
    __syncthreads();
    for (int i = blockIdx.x * blockDim.x + tid; i < total4; i += gridDim.x * blockDim.x) {
        long base = (long)i * 4;
        int f0 = (int)(base & 127);
        float4 v = *(const float4*)&hlin[base];
        float y0 = fmaxf(fmaf(v.x, sSc[f0 + 0], sSh[f0 + 0]), 0.f);
        float y1 = fmaxf(fmaf(v.y, sSc[f0 + 1], sSh[f0 + 1]), 0.f);
        float y2 = fmaxf(fmaf(v.z, sSc[f0 + 2], sSh[f0 + 2]), 0.f);
        float y3 = fmaxf(fmaf(v.w, sSc[f0 + 3], sSh[f0 + 3]), 0.f);
        uint2 o;
        o.x = (unsigned)(unsigned short)f2h(y0) | ((unsigned)(unsigned short)f2h(y1) << 16);
        o.y = (unsigned)(unsigned short)f2h(y2) | ((unsigned)(unsigned short)f2h(y3) << 16);
        *(uint2*)&hout[base] = o;
    }
}

// ---------------------------------------------------------------------------
// gemm_mid: h_lin[N,128] = gather7(h_fp16)[N,896] @ W[896,128] + b
// W pre-transposed: Wt[f][k] fp16. Also accumulates per-feature sum/sumsq.
// Block: 256 thr = 4 waves, tile 64 nodes x 128 feats; wave = 32 nodes x 64 feats
// (2x4 subtiles of 16x16, mfma_f32_16x16x32_f16).
// LDS pad +8 shorts per row: lane stride 272B -> <=2-way bank aliasing (free).
// ---------------------------------------------------------------------------
__global__ __launch_bounds__(256, 3) void gemm_mid_kernel(
        const short* __restrict__ hin, const int* __restrict__ idx,
        const short* __restrict__ Wt, const float* __restrict__ bvec,
        float* __restrict__ hlin, float* __restrict__ stats, int N) {
    __shared__ short sA[64 * 136];   // [node][k] for current j
    __shared__ short sB[128 * 136];  // [feat][k] for current j
    __shared__ float sstat[256];

    const int tid = threadIdx.x;
    const int wave = tid >> 6;
    const int lane = tid & 63;
    const int quad = lane >> 4;
    const int l16 = lane & 15;
    const int wm = wave & 1;        // node half (32 nodes)
    const int wf = wave >> 1;       // feat half (64 feats)
    const int m0 = blockIdx.x * 64;

    if (tid < 256) sstat[tid] = 0.f;

    f32x4 acc[2][4];
#pragma unroll
    for (int ni = 0; ni < 4; ++ni) {
        float bv = bvec[wf * 64 + ni * 16 + l16];
#pragma unroll
        for (int mi = 0; mi < 2; ++mi) {
            acc[mi][ni][0] = bv; acc[mi][ni][1] = bv; acc[mi][ni][2] = bv; acc[mi][ni][3] = bv;
        }
    }

    for (int j = 0; j < 7; ++j) {
        __syncthreads();
        // stage B: 128 feats x 128 k  (2048 chunks of 8 fp16)
#pragma unroll
        for (int i = tid; i < 2048; i += 256) {
            int f = i >> 4, ch = i & 15;
            *(f16x8*)&sB[f * 136 + ch * 8] =
                *(const f16x8*)&Wt[(long)f * 896 + j * 128 + ch * 8];
        }
        // stage A: 64 nodes x 128 k (gathered rows), 1024 chunks
#pragma unroll
        for (int i = tid; i < 1024; i += 256) {
            int nl = i >> 4, ch = i & 15;
            int n = m0 + nl;
            n = (n < N) ? n : (N - 1);
            long row = idx[n * 7 + j];
            *(f16x8*)&sA[nl * 136 + ch * 8] =
                *(const f16x8*)&hin[row * 128 + ch * 8];
        }
        __syncthreads();
#pragma unroll
        for (int k0 = 0; k0 < 128; k0 += 32) {
            f16x8 a[2], b[4];
#pragma unroll
            for (int mi = 0; mi < 2; ++mi)
                a[mi] = *(const f16x8*)&sA[(wm * 32 + mi * 16 + l16) * 136 + k0 + quad * 8];
#pragma unroll
            for (int ni = 0; ni < 4; ++ni)
                b[ni] = *(const f16x8*)&sB[(wf * 64 + ni * 16 + l16) * 136 + k0 + quad * 8];
#pragma unroll
            for (int mi = 0; mi < 2; ++mi)
#pragma unroll
                for (int ni = 0; ni < 4; ++ni)
                    acc[mi][ni] = __builtin_amdgcn_mfma_f32_16x16x32_f16(a[mi], b[ni], acc[mi][ni], 0, 0, 0);
        }
    }

    // epilogue: store h_lin fp32, accumulate per-feature stats
#pragma unroll
    for (int mi = 0; mi < 2; ++mi) {
#pragma unroll
        for (int ni = 0; ni < 4; ++ni) {
            int feat = wf * 64 + ni * 16 + l16;
            float s = 0.f, ss = 0.f;
#pragma unroll
            for (int r = 0; r < 4; ++r) {
                int node = m0 + wm * 32 + mi * 16 + quad * 4 + r;
                float v = acc[mi][ni][r];
                if (node < N) {
                    hlin[(long)node * 128 + feat] = v;
                    s += v;
                    ss += v * v;
                }
            }
            atomicAdd(&sstat[feat], s);
            atomicAdd(&sstat[128 + feat], ss);
        }
    }
    __syncthreads();
    if (tid < 128) {
        atomicAdd(&stats[tid], sstat[tid]);
        atomicAdd(&stats[128 + tid], sstat[128 + tid]);
    }
}

// ---------------------------------------------------------------------------
// gemm_final: out[N,36] = gather7(h_fp16)[N,896] @ Wl[896,36] + bl  (no BN)
// WtF: [48][896] fp16 (feats 36..47 zero). Block: 64 nodes, wave = 16 nodes x 48 feats.
// ---------------------------------------------------------------------------
__global__ __launch_bounds__(256) void gemm_final_kernel(
        const short* __restrict__ hin, const int* __restrict__ idx,
        const short* __restrict__ WtF, const float* __restrict__ bl,
        float* __restrict__ out, int N) {
    __shared__ short sA[64 * 136];
    __shared__ short sB[48 * 136];

    const int tid = threadIdx.x;
    const int wave = tid >> 6;
    const int lane = tid & 63;
    const int quad = lane >> 4;
    const int l16 = lane & 15;
    const int m0 = blockIdx.x * 64;

    f32x4 acc[3];
#pragma unroll
    for (int ni = 0; ni < 3; ++ni) {
        int feat = ni * 16 + l16;
        float bv = (feat < 36) ? bl[feat] : 0.f;
        acc[ni][0] = bv; acc[ni][1] = bv; acc[ni][2] = bv; acc[ni][3] = bv;
    }

    for (int j = 0; j < 7; ++j) {
        __syncthreads();
#pragma unroll
        for (int i = tid; i < 768; i += 256) {
            int f = i >> 4, ch = i & 15;
            *(f16x8*)&sB[f * 136 + ch * 8] =
                *(const f16x8*)&WtF[(long)f * 896 + j * 128 + ch * 8];
        }
#pragma unroll
        for (int i = tid; i < 1024; i += 256) {
            int nl = i >> 4, ch = i & 15;
            int n = m0 + nl;
            n = (n < N) ? n : (N - 1);
            long row = idx[n * 7 + j];
            *(f16x8*)&sA[nl * 136 + ch * 8] =
                *(const f16x8*)&hin[row * 128 + ch * 8];
        }
        __syncthreads();
#pragma unroll
        for (int k0 = 0; k0 < 128; k0 += 32) {
            f16x8 a = *(const f16x8*)&sA[(wave * 16 + l16) * 136 + k0 + quad * 8];
            f16x8 b[3];
#pragma unroll
            for (int ni = 0; ni < 3; ++ni)
                b[ni] = *(const f16x8*)&sB[(ni * 16 + l16) * 136 + k0 + quad * 8];
#pragma unroll
            for (int ni = 0; ni < 3; ++ni)
                acc[ni] = __builtin_amdgcn_mfma_f32_16x16x32_f16(a, b[ni], acc[ni], 0, 0, 0);
        }
    }

#pragma unroll
    for (int ni = 0; ni < 3; ++ni) {
        int feat = ni * 16 + l16;
        if (feat < 36) {
#pragma unroll
            for (int r = 0; r < 4; ++r) {
                int node = m0 + wave * 16 + quad * 4 + r;
                if (node < N) out[(long)node * 36 + feat] = acc[ni][r];
            }
        }
    }
}

// ---------------------------------------------------------------------------
extern "C" void kernel_launch(void* const* d_in, const int* in_sizes, int n_in,
                              void* d_out, int out_size, void* d_ws, size_t ws_size,
                              hipStream_t stream) {
    const float* x   = (const float*)d_in[0];
    const int*   idx = (const int*)d_in[1];
    const float* W0  = (const float*)d_in[2];
    const float* b0  = (const float*)d_in[3];
    const float* g0  = (const float*)d_in[4];
    const float* be0 = (const float*)d_in[5];
    const float* Wm  = (const float*)d_in[6];
    const float* bm  = (const float*)d_in[7];
    const float* gm  = (const float*)d_in[8];
    const float* bem = (const float*)d_in[9];
    const float* Wl  = (const float*)d_in[10];
    const float* bl  = (const float*)d_in[11];
    float* out = (float*)d_out;

    const int N = in_sizes[0] / 3;          // 40962
    const float invN = 1.0f / (float)N;

    char* ws = (char*)d_ws;
    size_t off = 0;
    auto alloc = [&](size_t bytes) -> void* {
        void* p = ws + off;
        off = (off + bytes + 255) & ~(size_t)255;
        return p;
    };
    short* WtM   = (short*)alloc(14UL * 128 * 896 * 2);
    short* WtF   = (short*)alloc(48UL * 896 * 2);
    float* stats = (float*)alloc(15UL * 256 * 4);
    float* hlin  = (float*)alloc((size_t)N * 128 * 4);
    short* hA    = (short*)alloc((size_t)N * 128 * 2);
    short* hB    = (short*)alloc((size_t)N * 128 * 2);

    {
        long total = 14L * 896 * 128 + 48L * 896 + 15L * 256;
        int blocks = (int)((total + 255) / 256);
        prep_kernel<<<blocks, 256, 0, stream>>>(Wm, Wl, WtM, WtF, stats);
    }

    layer0_kernel<<<512, 128, 0, stream>>>(x, idx, W0, b0, hlin, stats, N);

    int total4 = N * 32;  // N*128/4
    bn_relu_kernel<<<1024, 256, 0, stream>>>(hlin, stats, g0, be0,
                                             (unsigned short*)hA, total4, invN);

    const int gblocks = (N + 63) / 64;
    short* hin = hA;
    short* hout = hB;
    for (int L = 0; L < 14; ++L) {
        gemm_mid_kernel<<<gblocks, 256, 0, stream>>>(
            hin, idx, WtM + (size_t)L * 128 * 896, bm + L * 128,
            hlin, stats + (L + 1) * 256, N);
        bn_relu_kernel<<<1024, 256, 0, stream>>>(
            hlin, stats + (L + 1) * 256, gm + L * 128, bem + L * 128,
            (unsigned short*)hout, total4, invN);
        short* t = hin; hin = hout; hout = t;
    }

    gemm_final_kernel<<<gblocks, 256, 0, stream>>>(hin, idx, WtF, bl, out, N);
}